// Round 13
// baseline (889.064 us; speedup 1.0000x reference)
//
#include <hip/hip_runtime.h>

typedef unsigned long long u64;
typedef float f32x4 __attribute__((ext_vector_type(4)));

#define THR 0.5f

__device__ __forceinline__ u64 rfl64(u64 v) {
  unsigned lo = (unsigned)__builtin_amdgcn_readfirstlane((int)(unsigned)v);
  unsigned hi = (unsigned)__builtin_amdgcn_readfirstlane((int)(unsigned)(v >> 32));
  return ((u64)hi << 32) | lo;
}
__device__ __forceinline__ u64 rdl64c(u64 v, int l) {  // compile-time lane
  unsigned lo = (unsigned)__builtin_amdgcn_readlane((int)(unsigned)v, l);
  unsigned hi = (unsigned)__builtin_amdgcn_readlane((int)(unsigned)(v >> 32), l);
  return ((u64)hi << 32) | lo;
}

// cxcywh -> ltrb + area, contraction OFF (bit-exact vs numpy for the >=0.5 test)
__device__ __forceinline__ void conv_box(const float4 b, float& l, float& t,
                                         float& r, float& bo, float& a) {
  #pragma clang fp contract(off)
  float hw = 0.5f * b.z;
  float hh = 0.5f * b.w;
  l = b.x - hw;
  t = b.y - hh;
  r = b.x + hw;
  bo = b.y + hh;
  a = (r - l) * (bo - t);
}

__global__ void k_zero(int* __restrict__ rank, int n) {
  int i = blockIdx.x * blockDim.x + threadIdx.x;
  if (i < n) rank[i] = 0;
}

__global__ void k_rank(const float* __restrict__ scores, int* __restrict__ rank,
                       int n, int jchunk) {
  int i = blockIdx.x * blockDim.x + threadIdx.x;
  if (i >= n) return;
  float si = scores[i];
  int j0 = blockIdx.y * jchunk;
  int j1 = min(j0 + jchunk, n);
  int c = 0;
  for (int j = j0; j < j1; ++j) {
    float sj = scores[j];
    c += ((sj > si) || (sj == si && j < i)) ? 1 : 0;
  }
  if (c) atomicAdd(rank + i, c);
}

__global__ void k_scatter(const float4* __restrict__ boxes, const int* __restrict__ rank,
                          float* __restrict__ sl, float* __restrict__ st,
                          float* __restrict__ sr, float* __restrict__ sb,
                          float* __restrict__ sa, int* __restrict__ sidx, int n) {
  int i = blockIdx.x * blockDim.x + threadIdx.x;
  if (i >= n) return;
  float l, t, r, b, a;
  conv_box(boxes[i], l, t, r, b, a);
  int k = rank[i];
  sl[k] = l; st[k] = t; sr[k] = r; sb[k] = b; sa[k] = a; sidx[k] = i;
}

// TRANSPOSED mask: maskT[w*n_pad + k] = suppression word w of row k.
// Writes coalesced over k. Also emits diag + band1. No clamp on inter
// (replicates the reference NMS path exactly).
__device__ __forceinline__ void mask_body(
    const float* __restrict__ sl, const float* __restrict__ st,
    const float* __restrict__ sr, const float* __restrict__ sb,
    const float* __restrict__ sa,
    u64* __restrict__ maskT, u64* __restrict__ diag, u64* __restrict__ band1,
    int n, int n_pad, int bx, int by) {
  #pragma clang fp contract(off)
  int k = bx * 256 + threadIdx.x;
  if (k >= n) return;
  int w = by;
  int jbase = w << 6;
  u64 word = 0;
  if (jbase + 63 > k) {
    float l = sl[k], t = st[k], r = sr[k], b = sb[k], a = sa[k];
    int jend = min(jbase + 64, n);
    for (int j = max(jbase, k + 1); j < jend; ++j) {
      float lmax = fmaxf(l, sl[j]);
      float tmax = fmaxf(t, st[j]);
      float rmin = fminf(r, sr[j]);
      float bmin = fminf(b, sb[j]);
      float wd = rmin - lmax;
      float hd = bmin - tmax;
      float inter = wd * hd;
      float denom = (a + sa[j]) - inter;
      float q = inter / denom;
      if (q >= THR) word |= 1ull << (j - jbase);
    }
  }
  maskT[(size_t)w * n_pad + k] = word;
  int kg = k >> 6;
  if (kg == w) diag[k] = word;
  if (w == kg + 1) band1[k] = word;
}

__global__ void k_mask(const float* __restrict__ sl, const float* __restrict__ st,
                       const float* __restrict__ sr, const float* __restrict__ sb,
                       const float* __restrict__ sa,
                       u64* __restrict__ maskT, u64* __restrict__ diag,
                       u64* __restrict__ band1, int n, int n_pad) {
  mask_body(sl, st, sr, sb, sa, maskT, diag, band1, n, n_pad,
            blockIdx.x, blockIdx.y);
}

// wave64 OR-reduce via DPP; result uniform.
__device__ __forceinline__ u64 wave_or_u64(u64 v) {
  unsigned lo = (unsigned)v, hi = (unsigned)(v >> 32);
#define DPP_OR(x, ctrl, rmask) \
  x |= (unsigned)__builtin_amdgcn_update_dpp(0, (int)(x), ctrl, rmask, 0xF, true)
  DPP_OR(lo, 0x111, 0xF); DPP_OR(hi, 0x111, 0xF);
  DPP_OR(lo, 0x112, 0xF); DPP_OR(hi, 0x112, 0xF);
  DPP_OR(lo, 0x114, 0xF); DPP_OR(hi, 0x114, 0xF);
  DPP_OR(lo, 0x118, 0xF); DPP_OR(hi, 0x118, 0xF);
  DPP_OR(lo, 0x142, 0xA); DPP_OR(hi, 0x142, 0xA);
  DPP_OR(lo, 0x143, 0xC); DPP_OR(hi, 0x143, 0xC);
#undef DPP_OR
  unsigned flo = (unsigned)__builtin_amdgcn_readlane((int)lo, 63);
  unsigned fhi = (unsigned)__builtin_amdgcn_readlane((int)hi, 63);
  return ((u64)fhi << 32) | flo;
}

#define REP32(M) M(0) M(1) M(2) M(3) M(4) M(5) M(6) M(7) \
                 M(8) M(9) M(10) M(11) M(12) M(13) M(14) M(15) \
                 M(16) M(17) M(18) M(19) M(20) M(21) M(22) M(23) \
                 M(24) M(25) M(26) M(27) M(28) M(29) M(30) M(31)

// ---------------------------------------------------------------------------
// Greedy serial NMS scan — 512 threads, TRANSPOSED mask. Fold loads are
// UNCONDITIONAL (kw-independent) -> prefetched a full group ahead; kw applied
// afterwards as register select-ORs. Wave 0: SALU/readlane chain + band DPP.
// Raw s_barrier + lgkmcnt drain keeps vmem prefetches in flight across groups.
// ---------------------------------------------------------------------------
__global__ __launch_bounds__(512, 1) void k_scan4(
    const u64* __restrict__ maskT, const u64* __restrict__ diag,
    const u64* __restrict__ band1, const int* __restrict__ sidx,
    float* __restrict__ keep, int n, int n_pad) {
  __shared__ u64 kws[160];
  __shared__ u64 pub[2][2];
  int t = threadIdx.x;
  int lane = t & 63;
  int ng = (n + 63) >> 6;
  u64 R1 = 0;
  u64 d_cur = 0, d_nx = 0, b1_cur = 0, b1_nx = 0;
  if (t < 64) {
    d_cur = diag[lane];  d_nx = diag[64 + lane];
    b1_cur = band1[lane]; b1_nx = band1[64 + lane];
    if (t < 2) { pub[0][t] = 0; pub[1][t] = 0; }
  }
  int w = (t - 128) >> 1, h = (t - 128) & 1;
  bool isfold = (t >= 128) && (w < ng);
  u64 acc = 0;
#define DECLQ(q) u64 QA##q = 0, QB##q = 0;
  REP32(DECLQ)
#undef DECLQ

  asm volatile("s_waitcnt lgkmcnt(0)" ::: "memory");
  __builtin_amdgcn_s_barrier();

  for (int g = 0; g < ng; ++g) {
    int base = g << 6;
    if (t < 64) {
      u64 pv = pub[g & 1][0] | pub[g & 1][1];
      u64 s = rfl64(pv) | R1;
      int valid = n - base;
      if (valid < 64) s |= (~0ull) << valid;
      u64 kw = 0;
#define SSTEP(BB, EQ) { u64 sup = (s >> (BB)) & 1ull; \
      kw |= (sup ^ 1ull) << (BB); s |= sup ? 0ull : (EQ); }
#define SCHUNK(B0v) \
      if (((~s >> (B0v)) & 0xFFull) != 0ull) { \
        u64 E0 = rdl64c(d_cur, (B0v)+0); u64 E1 = rdl64c(d_cur, (B0v)+1); \
        u64 E2 = rdl64c(d_cur, (B0v)+2); u64 E3 = rdl64c(d_cur, (B0v)+3); \
        u64 E4 = rdl64c(d_cur, (B0v)+4); u64 E5 = rdl64c(d_cur, (B0v)+5); \
        u64 E6 = rdl64c(d_cur, (B0v)+6); u64 E7 = rdl64c(d_cur, (B0v)+7); \
        SSTEP((B0v)+0, E0) SSTEP((B0v)+1, E1) SSTEP((B0v)+2, E2) SSTEP((B0v)+3, E3) \
        SSTEP((B0v)+4, E4) SSTEP((B0v)+5, E5) SSTEP((B0v)+6, E6) SSTEP((B0v)+7, E7) }
      SCHUNK(0) SCHUNK(8) SCHUNK(16) SCHUNK(24)
      SCHUNK(32) SCHUNK(40) SCHUNK(48) SCHUNK(56)
#undef SCHUNK
#undef SSTEP
      if (lane == 0) kws[g] = kw;
      u64 m = (u64)0 - ((kw >> lane) & 1ull);
      R1 = wave_or_u64(b1_cur & m);        // group g's bits for word g+1
      d_cur = d_nx;   d_nx  = diag[base + 128 + lane];
      b1_cur = b1_nx; b1_nx = band1[base + 128 + lane];
    } else if (isfold && w > g) {
      const ulonglong2* src2 =
          (const ulonglong2*)(maskT + (size_t)w * n_pad + base + (h << 5));
#define LD2(B, i0, i1, p) { ulonglong2 v = src2[p]; B##i0 = v.x; B##i1 = v.y; }
      if ((g & 1) == 0) {
        LD2(QA,0,1,0)   LD2(QA,2,3,1)   LD2(QA,4,5,2)   LD2(QA,6,7,3)
        LD2(QA,8,9,4)   LD2(QA,10,11,5) LD2(QA,12,13,6) LD2(QA,14,15,7)
        LD2(QA,16,17,8) LD2(QA,18,19,9) LD2(QA,20,21,10) LD2(QA,22,23,11)
        LD2(QA,24,25,12) LD2(QA,26,27,13) LD2(QA,28,29,14) LD2(QA,30,31,15)
      } else {
        LD2(QB,0,1,0)   LD2(QB,2,3,1)   LD2(QB,4,5,2)   LD2(QB,6,7,3)
        LD2(QB,8,9,4)   LD2(QB,10,11,5) LD2(QB,12,13,6) LD2(QB,14,15,7)
        LD2(QB,16,17,8) LD2(QB,18,19,9) LD2(QB,20,21,10) LD2(QB,22,23,11)
        LD2(QB,24,25,12) LD2(QB,26,27,13) LD2(QB,28,29,14) LD2(QB,30,31,15)
      }
#undef LD2
      if (g > 0) {
        u64 kk = kws[g - 1];
        if (kk) {
          unsigned kh = (unsigned)(kk >> (h << 5));
#define ORQA(q) { u64 mq = (u64)0 - (u64)((kh >> (q)) & 1u); acc |= QA##q & mq; }
#define ORQB(q) { u64 mq = (u64)0 - (u64)((kh >> (q)) & 1u); acc |= QB##q & mq; }
          if ((g & 1) == 0) { REP32(ORQB) } else { REP32(ORQA) }
#undef ORQA
#undef ORQB
        }
        if (w == g + 1) pub[(g + 1) & 1][h] = acc;  // seed for group g+1
      }
    }
    asm volatile("s_waitcnt lgkmcnt(0)" ::: "memory");
    __builtin_amdgcn_s_barrier();
  }
  for (int k = t; k < n; k += 512) {
    u64 kwv = kws[k >> 6];
    keep[sidx[k]] = ((kwv >> (k & 63)) & 1ull) ? 1.0f : 0.0f;
  }
}

// Pairwise IoU, original order, WITH clamp. Loose 2e-2 threshold -> fast rcp.
__device__ __forceinline__ float iou_one(float li, float ti, float ri, float bi, float ai,
                                         float lj, float tj, float rj, float bj, float aj) {
  float lmax = fmaxf(li, lj);
  float tmax = fmaxf(ti, tj);
  float rmin = fminf(ri, rj);
  float bmin = fminf(bi, bj);
  float w = fmaxf(rmin - lmax, 0.0f);
  float h = fmaxf(bmin - tmax, 0.0f);
  float inter = w * h;
  float denom = (ai + aj) - inter;
  return inter * __builtin_amdgcn_rcpf(denom);
}

__device__ __forceinline__ void iou_body(const float4* __restrict__ boxes,
                                         float* __restrict__ out,
                                         int n, int rpb, int bx, int by) {
  int nj4 = (n + 3) >> 2;
  int j4 = bx * 256 + threadIdx.x;
  if (j4 >= nj4) return;
  int j = j4 << 2;
  int jc1 = min(j + 1, n - 1), jc2 = min(j + 2, n - 1), jc3 = min(j + 3, n - 1);
  float l0,t0,r0,b0,a0, l1,t1,r1,b1,a1, l2,t2,r2,b2,a2, l3,t3,r3,b3,a3;
  conv_box(boxes[j],   l0,t0,r0,b0,a0);
  conv_box(boxes[jc1], l1,t1,r1,b1,a1);
  conv_box(boxes[jc2], l2,t2,r2,b2,a2);
  conv_box(boxes[jc3], l3,t3,r3,b3,a3);
  bool full = (j + 3) < n;
  for (int rr = 0; rr < rpb; ++rr) {
    int i = by * rpb + rr;
    if (i >= n) return;
    float li,ti,ri,bi,ai;
    conv_box(boxes[i], li,ti,ri,bi,ai);
    float4 o;
    o.x = iou_one(li,ti,ri,bi,ai, l0,t0,r0,b0,a0);
    o.y = iou_one(li,ti,ri,bi,ai, l1,t1,r1,b1,a1);
    o.z = iou_one(li,ti,ri,bi,ai, l2,t2,r2,b2,a2);
    o.w = iou_one(li,ti,ri,bi,ai, l3,t3,r3,b3,a3);
    size_t row = (size_t)i * n;
    if (full) {
      f32x4 ov = { o.x, o.y, o.z, o.w };
      __builtin_nontemporal_store(ov, reinterpret_cast<f32x4*>(out + row + j));
    } else {
      out[row + j] = o.x;
      if (j + 1 < n) out[row + j + 1] = o.y;
      if (j + 2 < n) out[row + j + 2] = o.z;
    }
  }
}

__global__ void k_iou(const float4* __restrict__ boxes, float* __restrict__ out,
                      int n, int rpb) {
  iou_body(boxes, out, n, rpb, blockIdx.x, blockIdx.y);
}

// Fused mask + IoU (independent work, disjoint outputs).
__global__ __launch_bounds__(256) void k_maskiou(
    const float* __restrict__ sl, const float* __restrict__ st,
    const float* __restrict__ sr, const float* __restrict__ sb,
    const float* __restrict__ sa,
    u64* __restrict__ maskT, u64* __restrict__ diag, u64* __restrict__ band1,
    int n_pad, const float4* __restrict__ boxes, float* __restrict__ out,
    int n, int rpb, int nbx, int nmask, int gx) {
  int id = blockIdx.x;
  if (id < nmask) {
    mask_body(sl, st, sr, sb, sa, maskT, diag, band1, n, n_pad,
              id % nbx, id / nbx);
  } else {
    int iid = id - nmask;
    iou_body(boxes, out, n, rpb, iid % gx, iid / gx);
  }
}

extern "C" void kernel_launch(void* const* d_in, const int* in_sizes, int n_in,
                              void* d_out, int out_size, void* d_ws, size_t ws_size,
                              hipStream_t stream) {
  const float* boxes = (const float*)d_in[0];
  const float* scores = (const float*)d_in[1];
  int n = in_sizes[1];
  float* out = (float*)d_out;
  size_t NN = (size_t)n * (size_t)n;
  float* keep = out + NN;

  int ng = (n + 63) >> 6;
  int n_pad = ng << 6;
  size_t maskT_sz = (size_t)ng * n_pad * 8;
  size_t dbsz = (size_t)ng * 64 + 128;
  size_t need = maskT_sz + dbsz * 8 * 2 + 256 + (size_t)n * 4 * 7;
  bool use_ws = (ws_size >= need);

  char* base = use_ws ? (char*)d_ws : (char*)d_out;
  size_t off = 0;
  u64* maskT = (u64*)(base + off); off += maskT_sz;
  u64* diag  = (u64*)(base + off); off += dbsz * 8;
  u64* band1 = (u64*)(base + off); off += dbsz * 8;
  off = (off + 255) & ~(size_t)255;
  float* sl  = (float*)(base + off); off += (size_t)n * 4;
  float* st_ = (float*)(base + off); off += (size_t)n * 4;
  float* sr  = (float*)(base + off); off += (size_t)n * 4;
  float* sb  = (float*)(base + off); off += (size_t)n * 4;
  float* sa  = (float*)(base + off); off += (size_t)n * 4;
  int* sidx  = (int*)(base + off); off += (size_t)n * 4;
  int* rank  = (int*)(base + off); off += (size_t)n * 4;

  int nb = (n + 255) / 256;
  k_zero<<<nb, 256, 0, stream>>>(rank, n);

  int jblocks = 40;
  int jchunk = (n + jblocks - 1) / jblocks;
  k_rank<<<dim3(nb, jblocks), 256, 0, stream>>>(scores, rank, n, jchunk);

  k_scatter<<<nb, 256, 0, stream>>>((const float4*)boxes, rank, sl, st_, sr, sb, sa, sidx, n);

  int rpb = 10;
  int nj4 = (n + 3) >> 2;
  int gx = (nj4 + 255) / 256;
  int gy = (n + rpb - 1) / rpb;

  if (use_ws) {
    int nmask = nb * ng;
    int total = nmask + gx * gy;
    k_maskiou<<<total, 256, 0, stream>>>(sl, st_, sr, sb, sa, maskT, diag, band1,
                                         n_pad, (const float4*)boxes, out,
                                         n, rpb, nb, nmask, gx);
    k_scan4<<<1, 512, 0, stream>>>(maskT, diag, band1, sidx, keep, n, n_pad);
  } else {
    k_mask<<<dim3(nb, ng), 256, 0, stream>>>(sl, st_, sr, sb, sa, maskT, diag,
                                             band1, n, n_pad);
    k_scan4<<<1, 512, 0, stream>>>(maskT, diag, band1, sidx, keep, n, n_pad);
    k_iou<<<dim3(gx, gy), 256, 0, stream>>>((const float4*)boxes, out, n, rpb);
  }
}